// Round 13
// baseline (78.195 us; speedup 1.0000x reference)
//
#include <hip/hip_runtime.h>
#include <hip/hip_bf16.h>
#include <stdint.h>

#define SEQ     4096
#define HIDDEN  640
#define HDIM    80
#define NH      8
#define NKV     2
#define WINDOW  512
#define SINK    4
#define BQG     32    // flash q-tile (shared by 4 heads)
#define BK      128   // flash key-tile
#define KSTR    104   // Ks row stride (bf16): 2-way banks on b128 reads
#define VSTR    136   // Vt/Pl row stride (bf16): 2-way banks (128+8)
#define VSTRK   40    // Vtk sink row stride

typedef __bf16 bf16x8 __attribute__((ext_vector_type(8)));
typedef float  f32x4  __attribute__((ext_vector_type(4)));

__device__ inline __bf16 f2bf(float f) {
    union { float f; uint32_t u; } x; x.f = f;
    uint32_t r = x.u + 0x7FFF + ((x.u >> 16) & 1);   // RNE, no NaN inputs
    union { unsigned short s; __bf16 b; } y; y.s = (unsigned short)(r >> 16);
    return y.b;
}
__device__ inline float bf2f(unsigned short u) {
    union { uint32_t u; float f; } c; c.u = ((uint32_t)u) << 16; return c.f;
}
__device__ inline float fexp2(float x) {
#if __has_builtin(__builtin_amdgcn_exp2f)
    return __builtin_amdgcn_exp2f(x);
#else
    return exp2f(x);
#endif
}
__device__ inline bf16x8 pack8(float4 a, float4 b) {
    bf16x8 r;
    r[0] = f2bf(a.x); r[1] = f2bf(a.y); r[2] = f2bf(a.z); r[3] = f2bf(a.w);
    r[4] = f2bf(b.x); r[5] = f2bf(b.y); r[6] = f2bf(b.z); r[7] = f2bf(b.w);
    return r;
}

// ---------------------------------------------------------------------------
// Weight prep: all transposes (1000 blocks of 32x32 tiles).
// ---------------------------------------------------------------------------
__global__ __launch_bounds__(256) void prep_kernel(
    const float* __restrict__ Wq, const float* __restrict__ Wk,
    const float* __restrict__ Wv, const float* __restrict__ Wo,
    __bf16* __restrict__ WqkvT, __bf16* __restrict__ WoT)
{
    const int wf  = blockIdx.x;
    const int tid = threadIdx.x;
    const float* src;
    __bf16* dstb;
    int idx, tiles_x, N;
    if (wf < 400)      { src = Wq; dstb = WqkvT;             idx = wf;       tiles_x = 20; N = 640; }
    else if (wf < 500) { src = Wk; dstb = WqkvT + 640 * 640; idx = wf - 400; tiles_x = 5;  N = 160; }
    else if (wf < 600) { src = Wv; dstb = WqkvT + 800 * 640; idx = wf - 500; tiles_x = 5;  N = 160; }
    else               { src = Wo; dstb = WoT;               idx = wf - 600; tiles_x = 20; N = 640; }
    const int n0 = (idx % tiles_x) * 32;
    const int k0 = (idx / tiles_x) * 32;

    __shared__ float t[32][33];
    const int tx = tid & 31, ty = tid >> 5;     // 32 x 8
    #pragma unroll
    for (int i = 0; i < 4; ++i) {
        int r = ty + 8 * i;
        t[r][tx] = src[(size_t)(k0 + r) * N + n0 + tx];
    }
    __syncthreads();
    #pragma unroll
    for (int i = 0; i < 4; ++i) {
        int r = ty + 8 * i;
        dstb[(size_t)(n0 + r) * 640 + k0 + tx] = f2bf(t[tx][r]);
    }
}

// ---------------------------------------------------------------------------
// MFMA bf16 GEMM (r12-proven BK=64 macro-step). CONVA: A is fp32, converted
// in-register during staging (A-threads read 8x float4 per step).
// ---------------------------------------------------------------------------
template <bool CONVA, typename OutT>
__global__ __launch_bounds__(512) void gemm_bf16_mfma(
    const void* __restrict__ Av, const __bf16* __restrict__ BT,
    OutT* __restrict__ C, int M, int N, int K, int ldc)
{
    __shared__ __bf16 As[2][2][128][40];   // [h][buf]
    __shared__ __bf16 Bs[2][2][128][40];
    const int BUFE = 128 * 40;

    const int tid  = threadIdx.x;
    const int wave = tid >> 6;
    const int lane = tid & 63;
    const int wr = wave >> 2, wc = wave & 3;
    const int l15 = lane & 15, lq = lane >> 4;
    const int m0 = blockIdx.y * 128, n0 = blockIdx.x * 128;

    f32x4 acc[4][2];
    #pragma unroll
    for (int m = 0; m < 4; ++m)
        #pragma unroll
        for (int n = 0; n < 2; ++n) acc[m][n] = (f32x4)0.0f;

    const int sArr  = tid >> 8;          // 0: stage A, 1: stage B
    const int sc    = tid & 255;
    const int srow  = sc >> 1;           // 0..127
    const int shalf = sc & 1;
    const int grow  = sArr ? n0 : m0;
    const size_t gb = (size_t)(grow + srow) * K + 16 * shalf;
    __bf16* ld0 = (sArr ? &Bs[0][0][0][0] : &As[0][0][0][0]) + srow * 40 + 16 * shalf;
    __bf16* ld1 = (sArr ? &Bs[1][0][0][0] : &As[1][0][0][0]) + srow * 40 + 16 * shalf;

    const int nk = K >> 6;               // macro-steps of 64
    bf16x8 r00, r01, r10, r11;

#define GLOAD(KS)                                                              \
    if (CONVA && sArr == 0) {                                                  \
        const float* p = (const float*)Av + gb + (size_t)(KS) * 64;            \
        float4 f0 = *(const float4*)(p);                                       \
        float4 f1 = *(const float4*)(p + 4);                                   \
        float4 f2 = *(const float4*)(p + 8);                                   \
        float4 f3 = *(const float4*)(p + 12);                                  \
        float4 f4 = *(const float4*)(p + 32);                                  \
        float4 f5 = *(const float4*)(p + 36);                                  \
        float4 f6 = *(const float4*)(p + 40);                                  \
        float4 f7 = *(const float4*)(p + 44);                                  \
        r00 = pack8(f0, f1); r01 = pack8(f2, f3);                              \
        r10 = pack8(f4, f5); r11 = pack8(f6, f7);                              \
    } else {                                                                   \
        const __bf16* p = (sArr ? BT : (const __bf16*)Av) + gb + (size_t)(KS) * 64; \
        r00 = *(const bf16x8*)(p);                                             \
        r01 = *(const bf16x8*)(p + 8);                                         \
        r10 = *(const bf16x8*)(p + 32);                                        \
        r11 = *(const bf16x8*)(p + 40);                                        \
    }

    // prologue: macro-step 0 into buffer 0
    GLOAD(0);
    *(bf16x8*)ld0       = r00;
    *(bf16x8*)(ld0 + 8) = r01;
    *(bf16x8*)ld1       = r10;
    *(bf16x8*)(ld1 + 8) = r11;
    __syncthreads();

    for (int ks = 0; ks < nk; ++ks) {
        const int cur = ks & 1;
        if (ks + 1 < nk) { GLOAD(ks + 1); }

        __builtin_amdgcn_s_setprio(1);
        #pragma unroll
        for (int h = 0; h < 2; ++h) {
            bf16x8 af[4], bfr[2];
            #pragma unroll
            for (int m = 0; m < 4; ++m)
                af[m] = *(const bf16x8*)&As[h][cur][wr * 64 + m * 16 + l15][8 * lq];
            #pragma unroll
            for (int n = 0; n < 2; ++n)
                bfr[n] = *(const bf16x8*)&Bs[h][cur][wc * 32 + n * 16 + l15][8 * lq];
            #pragma unroll
            for (int m = 0; m < 4; ++m)
                #pragma unroll
                for (int n = 0; n < 2; ++n)
                    acc[m][n] = __builtin_amdgcn_mfma_f32_16x16x32_bf16(af[m], bfr[n], acc[m][n], 0, 0, 0);
        }
        __builtin_amdgcn_s_setprio(0);

        if (ks + 1 < nk) {
            const int nb = (cur ^ 1) * BUFE;
            *(bf16x8*)(ld0 + nb)     = r00;
            *(bf16x8*)(ld0 + nb + 8) = r01;
            *(bf16x8*)(ld1 + nb)     = r10;
            *(bf16x8*)(ld1 + nb + 8) = r11;
        }
        __syncthreads();
    }
#undef GLOAD

    #pragma unroll
    for (int m = 0; m < 4; ++m) {
        #pragma unroll
        for (int n = 0; n < 2; ++n) {
            const int col = n0 + wc * 32 + n * 16 + l15;
            if (col < N) {
                const int rbase = m0 + wr * 64 + m * 16 + 4 * lq;
                #pragma unroll
                for (int r = 0; r < 4; ++r) {
                    if constexpr (sizeof(OutT) == 2)
                        C[(size_t)(rbase + r) * ldc + col] = f2bf(acc[m][n][r]);
                    else
                        C[(size_t)(rbase + r) * ldc + col] = acc[m][n][r];
                }
            }
        }
    }
}

// ---------------------------------------------------------------------------
// Fused RMSNorm+RoPE (blocks [0,2048): 2 rows each) and V-transpose
// (blocks [2048,2688): 32x32 tiles). 256 threads. (r12-proven)
// ---------------------------------------------------------------------------
__global__ __launch_bounds__(256) void normrope_vt_kernel(
    const unsigned short* __restrict__ qkvb, const float* __restrict__ cosb,
    const float* __restrict__ sinb, const float* __restrict__ qw,
    const float* __restrict__ kw, __bf16* __restrict__ qb,
    __bf16* __restrict__ kb, unsigned short* __restrict__ vtb)
{
    const int flat = blockIdx.x;
    const int tid  = threadIdx.x;

    __shared__ float red[4];
    __shared__ unsigned short t[32][33];

    if (flat < 2048) {
        const int half = tid >> 7;           // 0..1 -> row pair
        const int lt   = tid & 127;
        const int row  = flat * 2 + half;

        float c = 0.f, s = 0.f, wqv = 0.f, wkv = 0.f;
        if (lt < HDIM) {
            c   = cosb[(size_t)row * (HDIM / 2) + (lt >> 1)];
            s   = sinb[(size_t)row * (HDIM / 2) + (lt >> 1)];
            wqv = qw[lt];
            wkv = kw[lt];
        }
        const float sgn = (lt & 1) ? 1.0f : -1.0f;
        const float QSCALE = 0.11180339887498948f * 1.4426950408889634f;

        for (int hh = 0; hh < 10; ++hh) {
            const unsigned short* p = (hh < NH)
                ? qkvb + (size_t)row * 960 + hh * HDIM
                : qkvb + (size_t)row * 960 + HIDDEN + (hh - NH) * HDIM;
            float v = (lt < HDIM) ? bf2f(p[lt]) : 0.0f;
            float sq = v * v;
            #pragma unroll
            for (int off = 32; off; off >>= 1) sq += __shfl_down(sq, off);
            if ((lt & 63) == 0) red[half * 2 + (lt >> 6)] = sq;
            __syncthreads();
            float rms = rsqrtf((red[half * 2] + red[half * 2 + 1]) * (1.0f / HDIM) + 1e-5f);

            float w  = (hh < NH) ? wqv : wkv;
            float vn = v * rms * w;
            float vp = __shfl_xor(vn, 1);
            float o  = vn * c + sgn * vp * s;

            if (lt < HDIM) {
                if (hh < NH) qb[(size_t)row * HIDDEN + hh * HDIM + lt] = (__bf16)(o * QSCALE);
                else         kb[(size_t)row * (NKV * HDIM) + (hh - NH) * HDIM + lt] = (__bf16)o;
            }
            __syncthreads();
        }
        return;
    }

    // ---- V transpose: vtb[kvh][d][seq] ----
    const int idx = flat - 2048;             // 0..639
    const int s0 = (idx & 127) * 32;
    const int c0 = (idx >> 7) * 32;
    const int tx = tid & 31, ty = tid >> 5;  // 32 x 8
    #pragma unroll
    for (int i = 0; i < 4; ++i)
        t[ty + 8 * i][tx] = qkvb[(size_t)(s0 + ty + 8 * i) * 960 + 800 + c0 + tx];
    __syncthreads();
    #pragma unroll
    for (int i = 0; i < 4; ++i) {
        int g = c0 + ty + 8 * i;             // 0..159
        int kvh = g / HDIM, d = g % HDIM;
        vtb[((size_t)kvh * HDIM + d) * SEQ + s0 + tx] = t[tx][ty + 8 * i];
    }
}

// ---------------------------------------------------------------------------
// GQA-fused MFMA flash attention, BK=128, K/V DOUBLE-buffered (1 barrier
// per tile) + SINK PREPASS (8 MFMA replace the former full sink tile).
// Block = (32-query tile, kvh), 512 threads = 8 waves = 4 heads x 2 wave-rows.
// LDS 141 KB (1 block/CU). Sinks are provably window-disjoint when w_tile>0.
// Per tile: [load t+1 regs] S -> softmax -> PV -> write t+1 -> barrier.
// ---------------------------------------------------------------------------
__global__ __launch_bounds__(512) void flash_attn_mfma(
    const __bf16* __restrict__ qb, const __bf16* __restrict__ kb,
    const __bf16* __restrict__ vtb, __bf16* __restrict__ attnb)
{
    const int i0   = blockIdx.x * BQG;
    const int kvh  = blockIdx.y;
    const int tid  = threadIdx.x;        // 0..511
    const int w    = tid >> 6;           // 0..7
    const int h    = kvh * 4 + (w >> 1);
    const int wsub = w & 1;
    const int lane = tid & 63;
    const int l15  = lane & 15;
    const int lq   = lane >> 4;

    __shared__ __bf16 Ks[2][BK][KSTR];   // 53248 B
    __shared__ __bf16 Vt[2][HDIM][VSTR]; // 43520 B
    __shared__ __bf16 Pl[128][VSTR];     // 34816 B
    __shared__ __bf16 Ksk[16][KSTR];     //  3328 B (sink K, keys 0..15)
    __shared__ __bf16 Vtk[HDIM][VSTRK];  //  6400 B (sink V, keys 0..31)
    // total 141312 B

    // zero K pad columns 80..95 of BOTH buffers (512 = 2 bufs x 128 rows x 2)
    {
        int b = tid >> 8, r = (tid >> 1) & 127, c = HDIM + 8 * (tid & 1);
        *(float4*)&Ks[b][r][c] = make_float4(0.f, 0.f, 0.f, 0.f);
    }

    // window staging maps: 1280 chunks of 8 bf16 each (chunk = tid + 512*i)
    int koff[3], voff[3];
    __bf16* ksdst0[3];
    __bf16* vsdst0[3];
    bool act[3];
    #pragma unroll
    for (int i = 0; i < 3; ++i) {
        int c = tid + 512 * i;
        act[i] = (c < 1280);
        int cc = act[i] ? c : 0;
        koff[i] = (cc / 10) * (NKV * HDIM) + 8 * (cc % 10);
        voff[i] = (cc >> 4) * SEQ + 8 * (cc & 15);
        ksdst0[i] = &Ks[0][cc / 10][8 * (cc % 10)];
        vsdst0[i] = &Vt[0][cc >> 4][8 * (cc & 15)];
    }
    const size_t ksbuf = (size_t)BK * KSTR;
    const size_t vsbuf = (size_t)HDIM * VSTR;
    const __bf16* kbase = kb + kvh * HDIM;
    const __bf16* vbase = vtb + (size_t)kvh * HDIM * SEQ;

    // preload Q A-fragments
    bf16x8 qf[3];
    {
        const __bf16* qrow = qb + (size_t)(i0 + 16 * wsub + l15) * HIDDEN + h * HDIM;
        #pragma unroll
        for (int ks = 0; ks < 3; ++ks) {
            int off = 32 * ks + 8 * lq;
            if (off >= HDIM) off = 0;     // dummy: multiplied by zeroed K pad
            qf[ks] = *(const bf16x8*)&qrow[off];
        }
    }

    float m_i[4], l_i[4];
    f32x4 o[5];
    #pragma unroll
    for (int r = 0; r < 4; ++r) { m_i[r] = -1e30f; l_i[r] = 0.0f; }
    #pragma unroll
    for (int n = 0; n < 5; ++n) o[n] = (f32x4)0.0f;

    const int w_lo   = i0 - (WINDOW - 1);
    const int w_tile = (w_lo <= 0) ? 0 : (w_lo & ~(BK - 1));
    const int lastt  = (i0 + BQG - 1) & ~(BK - 1);
    const int n_win  = (lastt - w_tile) / BK + 1;
    const bool has_sink = (w_tile > 0);   // sinks disjoint from window (i-511>=129>3)

    // ---- prologue: stage tile 0 (regs->LDS) + sink K/V, one barrier ----
    bf16x8 krg[3], vrg[3];
    #pragma unroll
    for (int i = 0; i < 3; ++i) {
        if (act[i]) {
            krg[i] = *(const bf16x8*)&kbase[(size_t)w_tile * (NKV * HDIM) + koff[i]];
            vrg[i] = *(const bf16x8*)&vbase[(size_t)w_tile + voff[i]];
        }
    }
    if (has_sink) {
        if (tid < 160) {                 // Ksk: 16 rows x 10 chunks
            int r = tid / 10, c8 = tid % 10;
            *(bf16x8*)&Ksk[r][8 * c8] =
                *(const bf16x8*)&kbase[(size_t)r * (NKV * HDIM) + 8 * c8];
        } else if (tid < 192) {          // Ksk pad cols 80..95
            int r = (tid - 160) >> 1, c = HDIM + 8 * (tid & 1);
            *(float4*)&Ksk[r][c] = make_float4(0.f, 0.f, 0.f, 0.f);
        } else {                         // Vtk: 80 rows x 4 chunks (keys 0..31)
            int c = tid - 192;           // 0..319
            *(bf16x8*)&Vtk[c >> 2][8 * (c & 3)] =
                *(const bf16x8*)&vbase[(size_t)(c >> 2) * SEQ + 8 * (c & 3)];
        }
    }
    #pragma unroll
    for (int i = 0; i < 3; ++i) {
        if (act[i]) {
            *(bf16x8*)ksdst0[i] = krg[i];
            *(bf16x8*)vsdst0[i] = vrg[i];
        }
    }
    __syncthreads();

    // ---- sink prepass: 3 MFMA (S) + 5 MFMA (PV) ----
    if (has_sink) {
        f32x4 sk = (f32x4)0.0f;
        #pragma unroll
        for (int ks = 0; ks < 3; ++ks) {
            bf16x8 kf = *(const bf16x8*)&Ksk[l15][32 * ks + 8 * lq];
            sk = __builtin_amdgcn_mfma_f32_16x16x32_bf16(qf[ks], kf, sk, 0, 0, 0);
        }
        if (l15 >= SINK) {
            #pragma unroll
            for (int r = 0; r < 4; ++r) sk[r] = -1e30f;
        }
        #pragma unroll
        for (int r = 0; r < 4; ++r) {
            float rmax = sk[r];
            rmax = fmaxf(rmax, __shfl_xor(rmax, 1));
            rmax = fmaxf(rmax, __shfl_xor(rmax, 2));
            rmax = fmaxf(rmax, __shfl_xor(rmax, 4));
            rmax = fmaxf(rmax, __shfl_xor(rmax, 8));
            m_i[r] = rmax;                         // first contribution
            float pe = fexp2(sk[r] - rmax);
            Pl[16 * w + 4 * lq + r][l15]      = (__bf16)pe;
            Pl[16 * w + 4 * lq + r][16 + l15] = (__bf16)0.0f;
            float rsum = pe;
            rsum += __shfl_xor(rsum, 1);
            rsum += __shfl_xor(rsum, 2);
            rsum += __shfl_xor(rsum, 4);
            rsum += __shfl_xor(rsum, 8);
            l_i[r] = rsum;
        }
        #pragma unroll
        for (int n = 0; n < 5; ++n) {
            bf16x8 pf = *(const bf16x8*)&Pl[16 * w + l15][8 * lq];
            bf16x8 vf = *(const bf16x8*)&Vtk[16 * n + l15][8 * lq];
            o[n] = __builtin_amdgcn_mfma_f32_16x16x32_bf16(pf, vf, o[n], 0, 0, 0);
        }
    }

    // ---- main loop: window tiles only, 1 barrier/tile ----
    for (int t = 0; t < n_win; ++t) {
        const int cur = t & 1;
        const int j0 = w_tile + t * BK;
        const bool more = (t + 1 < n_win);

        if (more) {
            const int j1 = j0 + BK;
            #pragma unroll
            for (int i = 0; i < 3; ++i) {
                if (act[i]) {
                    krg[i] = *(const bf16x8*)&kbase[(size_t)j1 * (NKV * HDIM) + koff[i]];
                    vrg[i] = *(const bf16x8*)&vbase[(size_t)j1 + voff[i]];
                }
            }
        }

        // ---- S = Q K^T : 24 MFMA per wave ----
        f32x4 sacc[8];
        #pragma unroll
        for (int n = 0; n < 8; ++n) sacc[n] = (f32x4)0.0f;
        __builtin_amdgcn_s_setprio(1);
        #pragma unroll
        for (int ks = 0; ks < 3; ++ks) {
            #pragma unroll
            for (int n = 0; n < 8; ++n) {
                bf16x8 kf = *(const bf16x8*)&Ks[cur][n * 16 + l15][32 * ks + 8 * lq];
                sacc[n] = __builtin_amdgcn_mfma_f32_16x16x32_bf16(qf[ks], kf, sacc[n], 0, 0, 0);
            }
        }
        __builtin_amdgcn_s_setprio(0);

        // ---- mask ----
        const bool full = (j0 >= i0 - 480) && (j0 <= i0 - 128);
        if (!full) {
            #pragma unroll
            for (int n = 0; n < 8; ++n) {
                int j = j0 + 16 * n + l15;
                #pragma unroll
                for (int r = 0; r < 4; ++r) {
                    int i = i0 + 16 * wsub + 4 * lq + r;
                    bool allowed = (j <= i) && ((j >= i - (WINDOW - 1)) || (j < SINK));
                    if (!allowed) sacc[n][r] = -1e30f;
                }
            }
        }

        // ---- online softmax (exp2 domain, exact skip-rescale) ----
        #pragma unroll
        for (int r = 0; r < 4; ++r) {
            float rmax = sacc[0][r];
            #pragma unroll
            for (int n = 1; n < 8; ++n) rmax = fmaxf(rmax, sacc[n][r]);
            rmax = fmaxf(rmax, __shfl_xor(rmax, 1));
            rmax = fmaxf(rmax, __shfl_xor(rmax, 2));
            rmax = fmaxf(rmax, __shfl_xor(rmax, 4));
            rmax = fmaxf(rmax, __shfl_xor(rmax, 8));
            if (rmax > m_i[r]) {
                float alpha = fexp2(m_i[r] - rmax);
                m_i[r] = rmax;
                l_i[r] *= alpha;
                #pragma unroll
                for (int n = 0; n < 5; ++n) o[n][r] *= alpha;
            }
            float rsum = 0.0f;
            #pragma unroll
            for (int n = 0; n < 8; ++n) {
                float pe = fexp2(sacc[n][r] - m_i[r]);
                Pl[16 * w + 4 * lq + r][16 * n + l15] = (__bf16)pe;
                rsum += pe;
            }
            rsum += __shfl_xor(rsum, 1);
            rsum += __shfl_xor(rsum, 2);
            rsum += __shfl_xor(rsum, 4);
            rsum += __shfl_xor(rsum, 8);
            l_i[r] += rsum;
        }

        // ---- O += P V : 20 MFMA per wave ----
        __builtin_amdgcn_s_setprio(1);
        #pragma unroll
        for (int ks = 0; ks < 4; ++ks) {
            bf16x8 pf = *(const bf16x8*)&Pl[16 * w + l15][32 * ks + 8 * lq];
            #pragma unroll
            for (int n = 0; n < 5; ++n) {
                bf16x8 vf = *(const bf16x8*)&Vt[cur][16 * n + l15][32 * ks + 8 * lq];
                o[n] = __builtin_amdgcn_mfma_f32_16x16x32_bf16(pf, vf, o[n], 0, 0, 0);
            }
        }
        __builtin_amdgcn_s_setprio(0);

        // ---- write next tile into the other buffer, then one barrier ----
        if (more) {
            #pragma unroll
            for (int i = 0; i < 3; ++i) {
                if (act[i]) {
                    *(bf16x8*)(ksdst0[i] + (cur ^ 1) * ksbuf) = krg[i];
                    *(bf16x8*)(vsdst0[i] + (cur ^ 1) * vsbuf) = vrg[i];
                }
            }
            __syncthreads();
        }
    }

    // ---- epilogue ----
    #pragma unroll
    for (int r = 0; r < 4; ++r) {
        float inv = 1.0f / l_i[r];
        int row = i0 + 16 * wsub + 4 * lq + r;
        #pragma unroll
        for (int n = 0; n < 5; ++n)
            attnb[(size_t)row * HIDDEN + h * HDIM + 16 * n + l15] = (__bf16)(o[n][r] * inv);
    }
}

// ---------------------------------------------------------------------------
extern "C" void kernel_launch(void* const* d_in, const int* in_sizes, int n_in,
                              void* d_out, int out_size, void* d_ws, size_t ws_size,
                              hipStream_t stream)
{
    const float* x    = (const float*)d_in[0];
    const float* cosb = (const float*)d_in[1];
    const float* sinb = (const float*)d_in[2];
    const float* Wq   = (const float*)d_in[3];
    const float* Wk   = (const float*)d_in[4];
    const float* Wv   = (const float*)d_in[5];
    const float* Wo   = (const float*)d_in[6];
    const float* qw   = (const float*)d_in[7];
    const float* kw   = (const float*)d_in[8];
    float* out = (float*)d_out;

    char* ws = (char*)d_ws;
    __bf16* qkvb  = (__bf16*)ws;                                 // [4096][960]
    __bf16* xb    = qkvb + (size_t)SEQ * 960;                    // [4096][640] = attnb
    __bf16* qb    = xb   + (size_t)SEQ * HIDDEN;                 // [4096][640]
    __bf16* kb    = qb   + (size_t)SEQ * HIDDEN;                 // [4096][160]
    __bf16* vtb   = kb   + (size_t)SEQ * 160;                    // [2][80][4096]
    __bf16* WqkvT = vtb  + (size_t)2 * HDIM * SEQ;               // [1024][640]
    __bf16* WoT   = WqkvT + (size_t)1024 * HIDDEN;               // [640][640]

    prep_kernel<<<dim3(1000), dim3(256), 0, stream>>>(
        Wq, Wk, Wv, Wo, WqkvT, WoT);

    // QKV projection: fp32 x converted in-register during A-staging
    gemm_bf16_mfma<true, __bf16><<<dim3(8, SEQ / 128), dim3(512), 0, stream>>>(
        x, WqkvT, qkvb, SEQ, 960, HIDDEN, 960);

    normrope_vt_kernel<<<dim3(2688), dim3(256), 0, stream>>>(
        (const unsigned short*)qkvb, cosb, sinb, qw, kw, qb, kb,
        (unsigned short*)vtb);

    flash_attn_mfma<<<dim3(SEQ / BQG, NKV), dim3(512), 0, stream>>>(
        qb, kb, vtb, xb);

    gemm_bf16_mfma<false, float><<<dim3(HIDDEN / 128, SEQ / 128), dim3(512), 0, stream>>>(
        xb, WoT, out, SEQ, HIDDEN, HIDDEN, HIDDEN);
}

// Round 14
// 72.582 us; speedup vs baseline: 1.0773x; 1.0773x over previous
//
#include <hip/hip_runtime.h>
#include <hip/hip_bf16.h>
#include <stdint.h>

#define SEQ     4096
#define HIDDEN  640
#define HDIM    80
#define NH      8
#define NKV     2
#define WINDOW  512
#define SINK    4
#define BQG     32    // flash q-tile (shared by 4 heads)
#define BK      128   // flash key-tile
#define KSTR    104   // Ks row stride (bf16): 2-way banks on b128 reads
#define VSTR    136   // Vt/Pl row stride (bf16): 2-way banks (128+8)
#define VSTRK   40    // Vtk sink row stride

typedef __bf16 bf16x8 __attribute__((ext_vector_type(8)));
typedef float  f32x4  __attribute__((ext_vector_type(4)));

__device__ inline __bf16 f2bf(float f) {
    union { float f; uint32_t u; } x; x.f = f;
    uint32_t r = x.u + 0x7FFF + ((x.u >> 16) & 1);   // RNE, no NaN inputs
    union { unsigned short s; __bf16 b; } y; y.s = (unsigned short)(r >> 16);
    return y.b;
}
__device__ inline float bf2f(unsigned short u) {
    union { uint32_t u; float f; } c; c.u = ((uint32_t)u) << 16; return c.f;
}
__device__ inline float fexp2(float x) {
#if __has_builtin(__builtin_amdgcn_exp2f)
    return __builtin_amdgcn_exp2f(x);
#else
    return exp2f(x);
#endif
}

// ---------------------------------------------------------------------------
// Fused prep: x -> bf16 (blocks [0,2560)) + all weight transposes
// (blocks [2560,3560), 32x32 tiles).  (r12-proven)
// ---------------------------------------------------------------------------
__global__ __launch_bounds__(256) void prep_kernel(
    const float* __restrict__ x, const float* __restrict__ Wq,
    const float* __restrict__ Wk, const float* __restrict__ Wv,
    const float* __restrict__ Wo, __bf16* __restrict__ xb,
    __bf16* __restrict__ WqkvT, __bf16* __restrict__ WoT)
{
    const int flat = blockIdx.x;
    const int tid  = threadIdx.x;
    if (flat < 2560) {
        int i = flat * 256 + tid;
        const float4 v = *(const float4*)&x[4 * i];
        xb[4 * i + 0] = f2bf(v.x);
        xb[4 * i + 1] = f2bf(v.y);
        xb[4 * i + 2] = f2bf(v.z);
        xb[4 * i + 3] = f2bf(v.w);
        return;
    }
    const int wf = flat - 2560;
    const float* src;
    __bf16* dstb;
    int idx, tiles_x, N;
    if (wf < 400)      { src = Wq; dstb = WqkvT;             idx = wf;       tiles_x = 20; N = 640; }
    else if (wf < 500) { src = Wk; dstb = WqkvT + 640 * 640; idx = wf - 400; tiles_x = 5;  N = 160; }
    else if (wf < 600) { src = Wv; dstb = WqkvT + 800 * 640; idx = wf - 500; tiles_x = 5;  N = 160; }
    else               { src = Wo; dstb = WoT;               idx = wf - 600; tiles_x = 20; N = 640; }
    const int n0 = (idx % tiles_x) * 32;
    const int k0 = (idx / tiles_x) * 32;

    __shared__ float t[32][33];
    const int tx = tid & 31, ty = tid >> 5;     // 32 x 8
    #pragma unroll
    for (int i = 0; i < 4; ++i) {
        int r = ty + 8 * i;
        t[r][tx] = src[(size_t)(k0 + r) * N + n0 + tx];
    }
    __syncthreads();
    #pragma unroll
    for (int i = 0; i < 4; ++i) {
        int r = ty + 8 * i;
        dstb[(size_t)(n0 + r) * 640 + k0 + tx] = f2bf(t[tx][r]);
    }
}

// ---------------------------------------------------------------------------
// MFMA bf16 GEMM (r12-proven): 512 threads = 8 waves (2M x 4N), tile 128x128,
// macro-step BK=64 (two 32-wide sub-tiles in separate LDS arrays), dbuf LDS,
// single-step-ahead reg prefetch, 1 barrier per macro-step. K % 64 == 0.
// ---------------------------------------------------------------------------
template <typename OutT>
__global__ __launch_bounds__(512) void gemm_bf16_mfma(
    const __bf16* __restrict__ A, const __bf16* __restrict__ BT,
    OutT* __restrict__ C, int M, int N, int K, int ldc)
{
    __shared__ __bf16 As[2][2][128][40];   // [h][buf]
    __shared__ __bf16 Bs[2][2][128][40];
    const int BUFE = 128 * 40;

    const int tid  = threadIdx.x;
    const int wave = tid >> 6;
    const int lane = tid & 63;
    const int wr = wave >> 2, wc = wave & 3;
    const int l15 = lane & 15, lq = lane >> 4;
    const int m0 = blockIdx.y * 128, n0 = blockIdx.x * 128;

    f32x4 acc[4][2];
    #pragma unroll
    for (int m = 0; m < 4; ++m)
        #pragma unroll
        for (int n = 0; n < 2; ++n) acc[m][n] = (f32x4)0.0f;

    const int sArr  = tid >> 8;          // 0: stage A, 1: stage B
    const int sc    = tid & 255;
    const int srow  = sc >> 1;           // 0..127
    const int shalf = sc & 1;
    const __bf16* gsrc = sArr ? BT : A;
    const int     grow = sArr ? n0 : m0;
    const size_t  gb   = (size_t)(grow + srow) * K + 16 * shalf;
    __bf16* ld0 = (sArr ? &Bs[0][0][0][0] : &As[0][0][0][0]) + srow * 40 + 16 * shalf;
    __bf16* ld1 = (sArr ? &Bs[1][0][0][0] : &As[1][0][0][0]) + srow * 40 + 16 * shalf;

    const int nk = K >> 6;               // macro-steps of 64

    // prologue: macro-step 0 into buffer 0
    bf16x8 r00 = *(const bf16x8*)&gsrc[gb];
    bf16x8 r01 = *(const bf16x8*)&gsrc[gb + 8];
    bf16x8 r10 = *(const bf16x8*)&gsrc[gb + 32];
    bf16x8 r11 = *(const bf16x8*)&gsrc[gb + 40];
    *(bf16x8*)ld0       = r00;
    *(bf16x8*)(ld0 + 8) = r01;
    *(bf16x8*)ld1       = r10;
    *(bf16x8*)(ld1 + 8) = r11;
    __syncthreads();

    for (int ks = 0; ks < nk; ++ks) {
        const int cur = ks & 1;
        if (ks + 1 < nk) {
            const size_t gg = gb + (size_t)(ks + 1) * 64;
            r00 = *(const bf16x8*)&gsrc[gg];
            r01 = *(const bf16x8*)&gsrc[gg + 8];
            r10 = *(const bf16x8*)&gsrc[gg + 32];
            r11 = *(const bf16x8*)&gsrc[gg + 40];
        }

        __builtin_amdgcn_s_setprio(1);
        #pragma unroll
        for (int h = 0; h < 2; ++h) {
            bf16x8 af[4], bfr[2];
            #pragma unroll
            for (int m = 0; m < 4; ++m)
                af[m] = *(const bf16x8*)&As[h][cur][wr * 64 + m * 16 + l15][8 * lq];
            #pragma unroll
            for (int n = 0; n < 2; ++n)
                bfr[n] = *(const bf16x8*)&Bs[h][cur][wc * 32 + n * 16 + l15][8 * lq];
            #pragma unroll
            for (int m = 0; m < 4; ++m)
                #pragma unroll
                for (int n = 0; n < 2; ++n)
                    acc[m][n] = __builtin_amdgcn_mfma_f32_16x16x32_bf16(af[m], bfr[n], acc[m][n], 0, 0, 0);
        }
        __builtin_amdgcn_s_setprio(0);

        if (ks + 1 < nk) {
            const int nb = (cur ^ 1) * BUFE;
            *(bf16x8*)(ld0 + nb)     = r00;
            *(bf16x8*)(ld0 + nb + 8) = r01;
            *(bf16x8*)(ld1 + nb)     = r10;
            *(bf16x8*)(ld1 + nb + 8) = r11;
        }
        __syncthreads();
    }

    #pragma unroll
    for (int m = 0; m < 4; ++m) {
        #pragma unroll
        for (int n = 0; n < 2; ++n) {
            const int col = n0 + wc * 32 + n * 16 + l15;
            if (col < N) {
                const int rbase = m0 + wr * 64 + m * 16 + 4 * lq;
                #pragma unroll
                for (int r = 0; r < 4; ++r) {
                    if constexpr (sizeof(OutT) == 2)
                        C[(size_t)(rbase + r) * ldc + col] = f2bf(acc[m][n][r]);
                    else
                        C[(size_t)(rbase + r) * ldc + col] = acc[m][n][r];
                }
            }
        }
    }
}

// ---------------------------------------------------------------------------
// Fused RMSNorm+RoPE (blocks [0,2048): 2 rows each) and V-transpose
// (blocks [2048,2688): 32x32 tiles). 256 threads. (r12-proven)
// ---------------------------------------------------------------------------
__global__ __launch_bounds__(256) void normrope_vt_kernel(
    const unsigned short* __restrict__ qkvb, const float* __restrict__ cosb,
    const float* __restrict__ sinb, const float* __restrict__ qw,
    const float* __restrict__ kw, __bf16* __restrict__ qb,
    __bf16* __restrict__ kb, unsigned short* __restrict__ vtb)
{
    const int flat = blockIdx.x;
    const int tid  = threadIdx.x;

    __shared__ float red[4];
    __shared__ unsigned short t[32][33];

    if (flat < 2048) {
        const int half = tid >> 7;           // 0..1 -> row pair
        const int lt   = tid & 127;
        const int row  = flat * 2 + half;

        float c = 0.f, s = 0.f, wqv = 0.f, wkv = 0.f;
        if (lt < HDIM) {
            c   = cosb[(size_t)row * (HDIM / 2) + (lt >> 1)];
            s   = sinb[(size_t)row * (HDIM / 2) + (lt >> 1)];
            wqv = qw[lt];
            wkv = kw[lt];
        }
        const float sgn = (lt & 1) ? 1.0f : -1.0f;
        const float QSCALE = 0.11180339887498948f * 1.4426950408889634f;

        for (int hh = 0; hh < 10; ++hh) {
            const unsigned short* p = (hh < NH)
                ? qkvb + (size_t)row * 960 + hh * HDIM
                : qkvb + (size_t)row * 960 + HIDDEN + (hh - NH) * HDIM;
            float v = (lt < HDIM) ? bf2f(p[lt]) : 0.0f;
            float sq = v * v;
            #pragma unroll
            for (int off = 32; off; off >>= 1) sq += __shfl_down(sq, off);
            if ((lt & 63) == 0) red[half * 2 + (lt >> 6)] = sq;
            __syncthreads();
            float rms = rsqrtf((red[half * 2] + red[half * 2 + 1]) * (1.0f / HDIM) + 1e-5f);

            float w  = (hh < NH) ? wqv : wkv;
            float vn = v * rms * w;
            float vp = __shfl_xor(vn, 1);
            float o  = vn * c + sgn * vp * s;

            if (lt < HDIM) {
                if (hh < NH) qb[(size_t)row * HIDDEN + hh * HDIM + lt] = (__bf16)(o * QSCALE);
                else         kb[(size_t)row * (NKV * HDIM) + (hh - NH) * HDIM + lt] = (__bf16)o;
            }
            __syncthreads();
        }
        return;
    }

    // ---- V transpose: vtb[kvh][d][seq] ----
    const int idx = flat - 2048;             // 0..639
    const int s0 = (idx & 127) * 32;
    const int c0 = (idx >> 7) * 32;
    const int tx = tid & 31, ty = tid >> 5;  // 32 x 8
    #pragma unroll
    for (int i = 0; i < 4; ++i)
        t[ty + 8 * i][tx] = qkvb[(size_t)(s0 + ty + 8 * i) * 960 + 800 + c0 + tx];
    __syncthreads();
    #pragma unroll
    for (int i = 0; i < 4; ++i) {
        int g = c0 + ty + 8 * i;             // 0..159
        int kvh = g / HDIM, d = g % HDIM;
        vtb[((size_t)kvh * HDIM + d) * SEQ + s0 + tx] = t[tx][ty + 8 * i];
    }
}

// ---------------------------------------------------------------------------
// GQA-fused MFMA flash attention (r13): BK=128, K/V double-buffered
// (1 barrier/tile) + sink prepass. Block = (32-query tile, kvh),
// 512 threads = 8 waves. LDS 141 KB (1 block/CU).
// Per tile: [load t+1 regs] S -> softmax -> PV -> write t+1 -> barrier.
// ---------------------------------------------------------------------------
__global__ __launch_bounds__(512) void flash_attn_mfma(
    const __bf16* __restrict__ qb, const __bf16* __restrict__ kb,
    const __bf16* __restrict__ vtb, __bf16* __restrict__ attnb)
{
    const int i0   = blockIdx.x * BQG;
    const int kvh  = blockIdx.y;
    const int tid  = threadIdx.x;        // 0..511
    const int w    = tid >> 6;           // 0..7
    const int h    = kvh * 4 + (w >> 1);
    const int wsub = w & 1;
    const int lane = tid & 63;
    const int l15  = lane & 15;
    const int lq   = lane >> 4;

    __shared__ __bf16 Ks[2][BK][KSTR];   // 53248 B
    __shared__ __bf16 Vt[2][HDIM][VSTR]; // 43520 B
    __shared__ __bf16 Pl[128][VSTR];     // 34816 B
    __shared__ __bf16 Ksk[16][KSTR];     //  3328 B (sink K, keys 0..15)
    __shared__ __bf16 Vtk[HDIM][VSTRK];  //  6400 B (sink V, keys 0..31)

    // zero K pad columns 80..95 of BOTH buffers
    {
        int b = tid >> 8, r = (tid >> 1) & 127, c = HDIM + 8 * (tid & 1);
        *(float4*)&Ks[b][r][c] = make_float4(0.f, 0.f, 0.f, 0.f);
    }

    // window staging maps: 1280 chunks of 8 bf16 each (chunk = tid + 512*i)
    int koff[3], voff[3];
    __bf16* ksdst0[3];
    __bf16* vsdst0[3];
    bool act[3];
    #pragma unroll
    for (int i = 0; i < 3; ++i) {
        int c = tid + 512 * i;
        act[i] = (c < 1280);
        int cc = act[i] ? c : 0;
        koff[i] = (cc / 10) * (NKV * HDIM) + 8 * (cc % 10);
        voff[i] = (cc >> 4) * SEQ + 8 * (cc & 15);
        ksdst0[i] = &Ks[0][cc / 10][8 * (cc % 10)];
        vsdst0[i] = &Vt[0][cc >> 4][8 * (cc & 15)];
    }
    const size_t ksbuf = (size_t)BK * KSTR;
    const size_t vsbuf = (size_t)HDIM * VSTR;
    const __bf16* kbase = kb + kvh * HDIM;
    const __bf16* vbase = vtb + (size_t)kvh * HDIM * SEQ;

    // preload Q A-fragments
    bf16x8 qf[3];
    {
        const __bf16* qrow = qb + (size_t)(i0 + 16 * wsub + l15) * HIDDEN + h * HDIM;
        #pragma unroll
        for (int ks = 0; ks < 3; ++ks) {
            int off = 32 * ks + 8 * lq;
            if (off >= HDIM) off = 0;     // dummy: multiplied by zeroed K pad
            qf[ks] = *(const bf16x8*)&qrow[off];
        }
    }

    float m_i[4], l_i[4];
    f32x4 o[5];
    #pragma unroll
    for (int r = 0; r < 4; ++r) { m_i[r] = -1e30f; l_i[r] = 0.0f; }
    #pragma unroll
    for (int n = 0; n < 5; ++n) o[n] = (f32x4)0.0f;

    const int w_lo   = i0 - (WINDOW - 1);
    const int w_tile = (w_lo <= 0) ? 0 : (w_lo & ~(BK - 1));
    const int lastt  = (i0 + BQG - 1) & ~(BK - 1);
    const int n_win  = (lastt - w_tile) / BK + 1;
    const bool has_sink = (w_tile > 0);   // sinks disjoint from window

    // ---- prologue: stage tile 0 + sink K/V, one barrier ----
    bf16x8 krg[3], vrg[3];
    #pragma unroll
    for (int i = 0; i < 3; ++i) {
        if (act[i]) {
            krg[i] = *(const bf16x8*)&kbase[(size_t)w_tile * (NKV * HDIM) + koff[i]];
            vrg[i] = *(const bf16x8*)&vbase[(size_t)w_tile + voff[i]];
        }
    }
    if (has_sink) {
        if (tid < 160) {                 // Ksk: 16 rows x 10 chunks
            int r = tid / 10, c8 = tid % 10;
            *(bf16x8*)&Ksk[r][8 * c8] =
                *(const bf16x8*)&kbase[(size_t)r * (NKV * HDIM) + 8 * c8];
        } else if (tid < 192) {          // Ksk pad cols 80..95
            int r = (tid - 160) >> 1, c = HDIM + 8 * (tid & 1);
            *(float4*)&Ksk[r][c] = make_float4(0.f, 0.f, 0.f, 0.f);
        } else if (tid < 512) {          // Vtk: 80 rows x 4 chunks
            int c = tid - 192;           // 0..319
            *(bf16x8*)&Vtk[c >> 2][8 * (c & 3)] =
                *(const bf16x8*)&vbase[(size_t)(c >> 2) * SEQ + 8 * (c & 3)];
        }
    }
    #pragma unroll
    for (int i = 0; i < 3; ++i) {
        if (act[i]) {
            *(bf16x8*)ksdst0[i] = krg[i];
            *(bf16x8*)vsdst0[i] = vrg[i];
        }
    }
    __syncthreads();

    // ---- sink prepass: 3 MFMA (S) + 5 MFMA (PV) ----
    if (has_sink) {
        f32x4 sk = (f32x4)0.0f;
        #pragma unroll
        for (int ks = 0; ks < 3; ++ks) {
            bf16x8 kf = *(const bf16x8*)&Ksk[l15][32 * ks + 8 * lq];
            sk = __builtin_amdgcn_mfma_f32_16x16x32_bf16(qf[ks], kf, sk, 0, 0, 0);
        }
        if (l15 >= SINK) {
            #pragma unroll
            for (int r = 0; r < 4; ++r) sk[r] = -1e30f;
        }
        #pragma unroll
        for (int r = 0; r < 4; ++r) {
            float rmax = sk[r];
            rmax = fmaxf(rmax, __shfl_xor(rmax, 1));
            rmax = fmaxf(rmax, __shfl_xor(rmax, 2));
            rmax = fmaxf(rmax, __shfl_xor(rmax, 4));
            rmax = fmaxf(rmax, __shfl_xor(rmax, 8));
            m_i[r] = rmax;
            float pe = fexp2(sk[r] - rmax);
            Pl[16 * w + 4 * lq + r][l15]      = (__bf16)pe;
            Pl[16 * w + 4 * lq + r][16 + l15] = (__bf16)0.0f;
            float rsum = pe;
            rsum += __shfl_xor(rsum, 1);
            rsum += __shfl_xor(rsum, 2);
            rsum += __shfl_xor(rsum, 4);
            rsum += __shfl_xor(rsum, 8);
            l_i[r] = rsum;
        }
        #pragma unroll
        for (int n = 0; n < 5; ++n) {
            bf16x8 pf = *(const bf16x8*)&Pl[16 * w + l15][8 * lq];
            bf16x8 vf = *(const bf16x8*)&Vtk[16 * n + l15][8 * lq];
            o[n] = __builtin_amdgcn_mfma_f32_16x16x32_bf16(pf, vf, o[n], 0, 0, 0);
        }
    }

    // ---- main loop: window tiles only, 1 barrier/tile ----
    for (int t = 0; t < n_win; ++t) {
        const int cur = t & 1;
        const int j0 = w_tile + t * BK;
        const bool more = (t + 1 < n_win);

        if (more) {
            const int j1 = j0 + BK;
            #pragma unroll
            for (int i = 0; i < 3; ++i) {
                if (act[i]) {
                    krg[i] = *(const bf16x8*)&kbase[(size_t)j1 * (NKV * HDIM) + koff[i]];
                    vrg[i] = *(const bf16x8*)&vbase[(size_t)j1 + voff[i]];
                }
            }
        }

        // ---- S = Q K^T : 24 MFMA per wave ----
        f32x4 sacc[8];
        #pragma unroll
        for (int n = 0; n < 8; ++n) sacc[n] = (f32x4)0.0f;
        __builtin_amdgcn_s_setprio(1);
        #pragma unroll
        for (int ks = 0; ks < 3; ++ks) {
            #pragma unroll
            for (int n = 0; n < 8; ++n) {
                bf16x8 kf = *(const bf16x8*)&Ks[cur][n * 16 + l15][32 * ks + 8 * lq];
                sacc[n] = __builtin_amdgcn_mfma_f32_16x16x32_bf16(qf[ks], kf, sacc[n], 0, 0, 0);
            }
        }
        __builtin_amdgcn_s_setprio(0);

        // ---- mask ----
        const bool full = (j0 >= i0 - 480) && (j0 <= i0 - 128);
        if (!full) {
            #pragma unroll
            for (int n = 0; n < 8; ++n) {
                int j = j0 + 16 * n + l15;
                #pragma unroll
                for (int r = 0; r < 4; ++r) {
                    int i = i0 + 16 * wsub + 4 * lq + r;
                    bool allowed = (j <= i) && ((j >= i - (WINDOW - 1)) || (j < SINK));
                    if (!allowed) sacc[n][r] = -1e30f;
                }
            }
        }

        // ---- online softmax (exp2 domain, exact skip-rescale) ----
        #pragma unroll
        for (int r = 0; r < 4; ++r) {
            float rmax = sacc[0][r];
            #pragma unroll
            for (int n = 1; n < 8; ++n) rmax = fmaxf(rmax, sacc[n][r]);
            rmax = fmaxf(rmax, __shfl_xor(rmax, 1));
            rmax = fmaxf(rmax, __shfl_xor(rmax, 2));
            rmax = fmaxf(rmax, __shfl_xor(rmax, 4));
            rmax = fmaxf(rmax, __shfl_xor(rmax, 8));
            if (rmax > m_i[r]) {
                float alpha = fexp2(m_i[r] - rmax);
                m_i[r] = rmax;
                l_i[r] *= alpha;
                #pragma unroll
                for (int n = 0; n < 5; ++n) o[n][r] *= alpha;
            }
            float rsum = 0.0f;
            #pragma unroll
            for (int n = 0; n < 8; ++n) {
                float pe = fexp2(sacc[n][r] - m_i[r]);
                Pl[16 * w + 4 * lq + r][16 * n + l15] = (__bf16)pe;
                rsum += pe;
            }
            rsum += __shfl_xor(rsum, 1);
            rsum += __shfl_xor(rsum, 2);
            rsum += __shfl_xor(rsum, 4);
            rsum += __shfl_xor(rsum, 8);
            l_i[r] += rsum;
        }

        // ---- O += P V : 20 MFMA per wave ----
        __builtin_amdgcn_s_setprio(1);
        #pragma unroll
        for (int ks = 0; ks < 4; ++ks) {
            bf16x8 pf = *(const bf16x8*)&Pl[16 * w + l15][32 * ks + 8 * lq];
            #pragma unroll
            for (int n = 0; n < 5; ++n) {
                bf16x8 vf = *(const bf16x8*)&Vt[cur][16 * n + l15][32 * ks + 8 * lq];
                o[n] = __builtin_amdgcn_mfma_f32_16x16x32_bf16(pf, vf, o[n], 0, 0, 0);
            }
        }
        __builtin_amdgcn_s_setprio(0);

        // ---- write next tile into the other buffer, then one barrier ----
        if (more) {
            #pragma unroll
            for (int i = 0; i < 3; ++i) {
                if (act[i]) {
                    *(bf16x8*)(ksdst0[i] + (cur ^ 1) * ksbuf) = krg[i];
                    *(bf16x8*)(vsdst0[i] + (cur ^ 1) * vsbuf) = vrg[i];
                }
            }
            __syncthreads();
        }
    }

    // ---- epilogue ----
    #pragma unroll
    for (int r = 0; r < 4; ++r) {
        float inv = 1.0f / l_i[r];
        int row = i0 + 16 * wsub + 4 * lq + r;
        #pragma unroll
        for (int n = 0; n < 5; ++n)
            attnb[(size_t)row * HIDDEN + h * HDIM + 16 * n + l15] = (__bf16)(o[n][r] * inv);
    }
}

// ---------------------------------------------------------------------------
extern "C" void kernel_launch(void* const* d_in, const int* in_sizes, int n_in,
                              void* d_out, int out_size, void* d_ws, size_t ws_size,
                              hipStream_t stream)
{
    const float* x    = (const float*)d_in[0];
    const float* cosb = (const float*)d_in[1];
    const float* sinb = (const float*)d_in[2];
    const float* Wq   = (const float*)d_in[3];
    const float* Wk   = (const float*)d_in[4];
    const float* Wv   = (const float*)d_in[5];
    const float* Wo   = (const float*)d_in[6];
    const float* qw   = (const float*)d_in[7];
    const float* kw   = (const float*)d_in[8];
    float* out = (float*)d_out;

    char* ws = (char*)d_ws;
    __bf16* qkvb  = (__bf16*)ws;                                 // [4096][960]
    __bf16* xb    = qkvb + (size_t)SEQ * 960;                    // [4096][640] = attnb
    __bf16* qb    = xb   + (size_t)SEQ * HIDDEN;                 // [4096][640]
    __bf16* kb    = qb   + (size_t)SEQ * HIDDEN;                 // [4096][160]
    __bf16* vtb   = kb   + (size_t)SEQ * 160;                    // [2][80][4096]
    __bf16* WqkvT = vtb  + (size_t)2 * HDIM * SEQ;               // [1024][640]
    __bf16* WoT   = WqkvT + (size_t)1024 * HIDDEN;               // [640][640]

    prep_kernel<<<dim3(3560), dim3(256), 0, stream>>>(
        x, Wq, Wk, Wv, Wo, xb, WqkvT, WoT);

    gemm_bf16_mfma<__bf16><<<dim3(8, SEQ / 128), dim3(512), 0, stream>>>(
        xb, WqkvT, qkvb, SEQ, 960, HIDDEN, 960);

    normrope_vt_kernel<<<dim3(2688), dim3(256), 0, stream>>>(
        (const unsigned short*)qkvb, cosb, sinb, qw, kw, qb, kb,
        (unsigned short*)vtb);

    flash_attn_mfma<<<dim3(SEQ / BQG, NKV), dim3(512), 0, stream>>>(
        qb, kb, vtb, xb);

    gemm_bf16_mfma<float><<<dim3(HIDDEN / 128, SEQ / 128), dim3(512), 0, stream>>>(
        xb, WoT, out, SEQ, HIDDEN, HIDDEN, HIDDEN);
}